// Round 1
// 395.707 us; speedup vs baseline: 1.0160x; 1.0160x over previous
//
#include <hip/hip_runtime.h>

// ---------------------------------------------------------------------------
// FlashMMSequenceMixing (Hyena-style): B=8, L=2048, D=768, ORDER=128, FFT=4096
// R7 -> R8: GEMM rewritten as 256x256xBK64 8-phase schedule (m201 template):
//  - 512 thr / 8 waves (2Mx4N), wave tile 128x64, acc[8][4] f32x4
//  - 128 KiB dynamic LDS: A/B double-buffered K-tiles, XOR chunk swizzle
//    slot = chunk ^ (row&7)  (16B chunks; linear DMA dest, pre-swizzled src)
//  - per phase: {ds_read frag group || 2x global_load_lds_dwordx4 || 16 MFMA
//    in setprio(1)} ; s_waitcnt lgkmcnt(0); s_barrier
//  - counted vmcnt(6) ONLY at phases 4/8 (3 quarter-stages in flight);
//    epilogue drains vmcnt(2)->vmcnt(0) so vmcnt==0 at s_endpgm (R7 rule).
// Hazard windows verified: each LDS quarter is rewritten exactly one barrier
// after its last reader phase; vmcnt(6) fences guarantee landing before the
// first reader of the new tile.
// ---------------------------------------------------------------------------

typedef __bf16 bf16x8 __attribute__((ext_vector_type(8)));
typedef float  f32x4  __attribute__((ext_vector_type(4)));

#define AS1 __attribute__((address_space(1)))
#define AS3 __attribute__((address_space(3)))
#define GLD16(gp, lp) __builtin_amdgcn_global_load_lds((AS1 void*)(void*)(gp), (AS3 void*)(void*)(lp), 16, 0, 0)

// compiler-visible fences (memory clobber pins LDS/global ops to program order)
#define LGKM_BAR       __asm__ __volatile__("s_waitcnt lgkmcnt(0)\n\ts_barrier" ::: "memory")
#define VM_LGKM_BAR(N) __asm__ __volatile__("s_waitcnt vmcnt(" #N ") lgkmcnt(0)\n\ts_barrier" ::: "memory")

__device__ __forceinline__ unsigned short f2b(float f) {
    unsigned u = __builtin_bit_cast(unsigned, f);
    unsigned r = (u + 0x7fffu + ((u >> 16) & 1u)) >> 16;
    return (unsigned short)r;
}
__device__ __forceinline__ float b2f(unsigned short h) {
    unsigned u = ((unsigned)h) << 16;
    return __builtin_bit_cast(float, u);
}
__device__ __forceinline__ float b2f_lo(unsigned u) {
    return __builtin_bit_cast(float, u << 16);
}
__device__ __forceinline__ float b2f_hi(unsigned u) {
    return __builtin_bit_cast(float, u & 0xffff0000u);
}

__device__ __forceinline__ float2 cmul(float2 a, float2 b) {
    return make_float2(a.x * b.x - a.y * b.y, a.x * b.y + a.y * b.x);
}
__device__ __forceinline__ float2 cadd(float2 a, float2 b) { return make_float2(a.x + b.x, a.y + b.y); }
__device__ __forceinline__ float2 csub(float2 a, float2 b) { return make_float2(a.x - b.x, a.y - b.y); }

// ------------------------- 16-point register DFT ---------------------------
#define BFLY(i,j)   { float2 ta=x[i], tb=x[j]; x[i]=cadd(ta,tb); x[j]=csub(ta,tb); }
#define BFLYW(i,j,w){ float2 ta=x[i], tb=x[j]; x[i]=cadd(ta,tb); x[j]=cmul(csub(ta,tb),(w)); }
#define BFLYI(i,j)  { float2 ta=x[i], tb=x[j]; x[i]=cadd(ta,tb); float2 tt=csub(ta,tb); x[j]=make_float2(-dd*tt.y, dd*tt.x); }
#define CSWAP(i,j)  { float2 tt=x[i]; x[i]=x[j]; x[j]=tt; }

template<int DIR, bool UZ>
__device__ __forceinline__ void dft16(float2* x) {
    const float dd = (float)DIR;
    const float C1 = 0.92387953251128674f, S1 = 0.38268343236508977f, R2 = 0.70710678118654752f;
    const float2 W1 = make_float2( C1, dd*S1);
    const float2 W2 = make_float2( R2, dd*R2);
    const float2 W3 = make_float2( S1, dd*C1);
    const float2 W5 = make_float2(-S1, dd*C1);
    const float2 W6 = make_float2(-R2, dd*R2);
    const float2 W7 = make_float2(-C1, dd*S1);
    if (UZ) {
        x[8]  = x[0];
        x[9]  = cmul(x[1], W1);
        x[10] = cmul(x[2], W2);
        x[11] = cmul(x[3], W3);
        x[12] = make_float2(-dd*x[4].y, dd*x[4].x);
        x[13] = cmul(x[5], W5);
        x[14] = cmul(x[6], W6);
        x[15] = cmul(x[7], W7);
    } else {
        BFLY(0,8); BFLYW(1,9,W1); BFLYW(2,10,W2); BFLYW(3,11,W3);
        BFLYI(4,12); BFLYW(5,13,W5); BFLYW(6,14,W6); BFLYW(7,15,W7);
    }
    BFLY(0,4);  BFLYW(1,5,W2);  BFLYI(2,6);   BFLYW(3,7,W6);
    BFLY(8,12); BFLYW(9,13,W2); BFLYI(10,14); BFLYW(11,15,W6);
    BFLY(0,2);  BFLYI(1,3);  BFLY(4,6);   BFLYI(5,7);
    BFLY(8,10); BFLYI(9,11); BFLY(12,14); BFLYI(13,15);
    BFLY(0,1); BFLY(2,3); BFLY(4,5); BFLY(6,7);
    BFLY(8,9); BFLY(10,11); BFLY(12,13); BFLY(14,15);
    CSWAP(1,8); CSWAP(2,4); CSWAP(3,12); CSWAP(5,10); CSWAP(7,14); CSWAP(11,13);
}

// log-depth twiddle powers (serial chain 15 -> depth 4)
__device__ __forceinline__ void twiddle_mul(float2* x, float ang) {
    float s, c; __sincosf(ang, &s, &c);
    float2 w[16];
    w[1] = make_float2(c, s);
    w[2] = cmul(w[1], w[1]);
    w[3] = cmul(w[2], w[1]);  w[4] = cmul(w[2], w[2]);
    w[5] = cmul(w[4], w[1]);  w[6] = cmul(w[4], w[2]);
    w[7] = cmul(w[4], w[3]);  w[8] = cmul(w[4], w[4]);
    w[9]  = cmul(w[8], w[1]); w[10] = cmul(w[8], w[2]);
    w[11] = cmul(w[8], w[3]); w[12] = cmul(w[8], w[4]);
    w[13] = cmul(w[8], w[5]); w[14] = cmul(w[8], w[6]);
    w[15] = cmul(w[8], w[7]);
    #pragma unroll
    for (int k = 1; k < 16; ++k) x[k] = cmul(x[k], w[k]);
}

#define TWO_PI 6.283185307179586f
__device__ __forceinline__ void fft4096_fwd(float2* x, float2* lds, int t) {
    dft16<-1, true>(x);
    twiddle_mul(x, -(float)t * (TWO_PI / 4096.0f));
    #pragma unroll
    for (int k1 = 0; k1 < 16; ++k1) lds[k1 * 272 + t] = x[k1];
    __syncthreads();
    const int hi = t >> 4, lo = t & 15;
    #pragma unroll
    for (int t1 = 0; t1 < 16; ++t1) x[t1] = lds[hi * 272 + t1 * 16 + lo];
    dft16<-1, false>(x);
    twiddle_mul(x, -(float)lo * (TWO_PI / 256.0f));
    __syncthreads();
    #pragma unroll
    for (int k2 = 0; k2 < 16; ++k2) lds[t * 17 + k2] = x[k2];
    __syncthreads();
    #pragma unroll
    for (int t0 = 0; t0 < 16; ++t0) x[t0] = lds[(hi * 16 + t0) * 17 + lo];
    dft16<-1, false>(x);
}

__device__ __forceinline__ void fft4096_inv(float2* x, float2* lds, int t) {
    const int hi = t >> 4, lo = t & 15;
    dft16<1, false>(x);
    __syncthreads();
    #pragma unroll
    for (int t0 = 0; t0 < 16; ++t0) lds[(hi * 16 + t0) * 17 + lo] = x[t0];
    __syncthreads();
    #pragma unroll
    for (int k2 = 0; k2 < 16; ++k2) x[k2] = lds[t * 17 + k2];
    twiddle_mul(x, (float)lo * (TWO_PI / 256.0f));
    dft16<1, false>(x);
    __syncthreads();
    #pragma unroll
    for (int t1 = 0; t1 < 16; ++t1) lds[hi * 272 + t1 * 16 + lo] = x[t1];
    __syncthreads();
    #pragma unroll
    for (int k1 = 0; k1 < 16; ++k1) x[k1] = lds[k1 * 272 + t];
    twiddle_mul(x, (float)t * (TWO_PI / 4096.0f));
    dft16<1, false>(x);
}

// ------------------------------- filter MLP --------------------------------
__global__ __launch_bounds__(256) void filter_k_kernel(
    const float* __restrict__ z, const float* __restrict__ sf,
    const float* __restrict__ eo, const float* __restrict__ eo_b,
    const float* __restrict__ oo1, const float* __restrict__ oo1_b,
    const float* __restrict__ oo2, const float* __restrict__ oo2_b,
    const float* __restrict__ oh, float* __restrict__ kfil)
{
    __shared__ float h3buf[8][128];
    __shared__ float htmp[2][128];
    const int t = threadIdx.x;
    const int l0 = blockIdx.x * 8;
    const int half = t >> 7;
    const int o = t & 127;
    const float sfo = sf[o];
    for (int p = 0; p < 4; ++p) {
        const int li = p * 2 + half;
        const int l = l0 + li;
        float a = eo_b[o];
        #pragma unroll
        for (int e = 0; e < 5; ++e) a += z[l * 5 + e] * eo[e * 128 + o];
        htmp[half][o] = sinf(sfo * a);
        __syncthreads();
        float a2 = oo1_b[o];
        for (int q = 0; q < 128; ++q) a2 += htmp[half][q] * oo1[q * 128 + o];
        const float h2 = sinf(sfo * a2);
        __syncthreads();
        htmp[half][o] = h2;
        __syncthreads();
        float a3 = oo2_b[o];
        for (int q = 0; q < 128; ++q) a3 += htmp[half][q] * oo2[q * 128 + o];
        h3buf[li][o] = sinf(sfo * a3);
        __syncthreads();
    }
    const float MIND = -3.070113457325394f;
    const float MAXD = -15.350567286626972f;
    for (int c = 0; c < 3; ++c) {
        const int h = t + c * 256;
        float acc[8];
        #pragma unroll
        for (int li = 0; li < 8; ++li) acc[li] = 0.f;
        for (int q = 0; q < 128; ++q) {
            const float w = oh[q * 768 + h];
            #pragma unroll
            for (int li = 0; li < 8; ++li) acc[li] += h3buf[li][q] * w;
        }
        const float delta = fabsf(MIND + (MAXD - MIND) * (float)h * (1.0f / 767.0f));
        #pragma unroll
        for (int li = 0; li < 8; ++li) {
            const int l = l0 + li;
            const float tt = (float)l * (1.0f / 2047.0f);
            kfil[h * 2048 + l] = acc[li] * expf(-tt * delta);
        }
    }
}

// --------------------------- filter FFT ------------------------------------
__global__ __launch_bounds__(256, 4) void filter_fft_kernel(
    const float* __restrict__ kfil, float2* __restrict__ Kf)
{
    __shared__ float2 lds[4352];
    const int d = blockIdx.x, t = threadIdx.x;
    float2 x[16];
    #pragma unroll
    for (int r = 0; r < 8; ++r) x[r] = make_float2(kfil[d * 2048 + r * 256 + t], 0.f);
    fft4096_fwd(x, lds, t);
    #pragma unroll
    for (int k3 = 0; k3 < 16; ++k3) Kf[d * 4096 + k3 * 256 + t] = x[k3];
}

// --------------------------- conversions/transposes ------------------------
__global__ __launch_bounds__(256) void convert_u_kernel(
    const float* __restrict__ u, unsigned short* __restrict__ ub)
{
    const int g = blockIdx.x * 256 + threadIdx.x;
    const float4 v = ((const float4*)u)[g];
    uint2 o;
    o.x = (unsigned)f2b(v.x) | ((unsigned)f2b(v.y) << 16);
    o.y = (unsigned)f2b(v.z) | ((unsigned)f2b(v.w) << 16);
    ((uint2*)ub)[g] = o;
}

__global__ __launch_bounds__(256) void transpose_W_kernel(
    const float* __restrict__ W, unsigned short* __restrict__ Wt, int K, int N)
{
    __shared__ float tile[32][33];
    const int n0 = blockIdx.x * 32, k0 = blockIdx.y * 32;
    const int tx = threadIdx.x & 31, ty = threadIdx.x >> 5;
    #pragma unroll
    for (int r = 0; r < 4; ++r) {
        const int kk = ty + r * 8;
        tile[kk][tx] = W[(k0 + kk) * N + n0 + tx];
    }
    __syncthreads();
    #pragma unroll
    for (int r = 0; r < 4; ++r) {
        const int nn = ty + r * 8;
        Wt[(n0 + nn) * K + k0 + tx] = f2b(tile[tx][nn]);
    }
}

__global__ __launch_bounds__(256) void transpose_Y_kernel(
    const unsigned short* __restrict__ Y, unsigned short* __restrict__ Yt)
{
    __shared__ unsigned short tile[32][34];
    const int bx = blockIdx.x;
    const int l0 = (bx & 63) * 32;
    const int tmp = bx >> 6;
    const int d0 = (tmp % 24) * 32;
    const int b  = tmp / 24;
    const int tx = threadIdx.x & 31, ty = threadIdx.x >> 5;
    #pragma unroll
    for (int r = 0; r < 4; ++r) {
        const int dd = ty + r * 8;
        tile[dd][tx] = Y[(b * 768 + d0 + dd) * 2048 + l0 + tx];
    }
    __syncthreads();
    #pragma unroll
    for (int r = 0; r < 4; ++r) {
        const int ll = ty + r * 8;
        Yt[(b * 2048 + l0 + ll) * 768 + d0 + tx] = tile[tx][ll];
    }
}

// ------------------------------- bf16 GEMM ---------------------------------
// 256x256 tile, BK=64, 8 waves (2Mx4N), wave tile 128x64, 8-phase schedule.
// LDS (dynamic, 128 KiB): As[2][256][64], Bs[2][256][64] bf16; within a row's
// 128B the 16B chunk is XOR-swizzled: LDS slot (row, c) holds data chunk
// c ^ (row & 7)  -> conflict-free ds_read_b128 fragment reads, and the
// global_load_lds destination stays linear (pre-swizzled global source).
//
// Per iteration (2 K-tiles), phases P1..P8; per K-tile quadrant order
// Qa=[M0xN0] Qb=[M0xN1] Qc=[M1xN1] Qd=[M1xN0] (Qd reuses regs, 0 ds_reads).
// Stage schedule (quarter q = 64 rows = 2 GLD16/thread), tile n0=2i+2 -> buf0,
// n1=2i+3 -> buf1:
//   P1: buf1.Aq1,Aq3 (tile 2i+1 tail)   P5: buf0.Aq1,Aq3 (n0)
//   P2: buf0.Aq0,Aq2 (n0)               P6: buf1.Aq0,Aq2 (n1)
//   P3: buf0.Bq0,Bq1 (n0)               P7: buf1.Bq0,Bq1 (n1)
//   P4: buf0.Bq2,Bq3 (n0)  vmcnt(6)     P8: buf1.Bq2,Bq3 (n1)  vmcnt(6)
// Every quarter is rewritten exactly one barrier after its last reader phase;
// vmcnt(6) at P4/P8 forces everything except the youngest 3 quarters landed,
// which is exactly the set the next 4 phases read.  Epilogue (last 2 tiles):
// only the P1 stage remains; fences tighten to vmcnt(2) at P4 and vmcnt(0)
// at P6, so vmcnt==0 at kernel exit (no in-flight DMA into reallocated LDS).
// mode 0: launched dim3(nCol, nRow); mode 1: launched dim3(nRow, nCol).
__global__ __launch_bounds__(512, 2) void gemm256_kernel(
    const unsigned short* __restrict__ A,
    const unsigned short* __restrict__ Bm,
    const float* __restrict__ bias,
    unsigned short* __restrict__ outb,
    float* __restrict__ outf,
    int mode)
{
    extern __shared__ __align__(16) unsigned short lds[];
    unsigned short* As = lds;            // [2][256][64]  2*32 KiB
    unsigned short* Bs = lds + 32768;    // [2][256][64]  2*32 KiB
    const int t = threadIdx.x;
    const int wv = t >> 6, lane = t & 63;
    const int row0 = (mode == 0 ? blockIdx.y : blockIdx.x) * 256;
    const int col0 = (mode == 0 ? blockIdx.x : blockIdx.y) * 256;
    const int wr = wv >> 2, wc = wv & 3;
    const int frow = lane & 15, kc = lane >> 4;

    f32x4 acc[8][4] = {};

    // staging: thread t covers (row = q*64 + (t>>3), slot = t&7); the slot
    // holds data chunk slot ^ (row&7) = (t&7) ^ ((t>>3)&7) (q*64 = 0 mod 8).
    const int srow = t >> 3;
    const int cdat = (t & 7) ^ (srow & 7);
    const unsigned short* gA = A  + (row0 + srow) * 768 + cdat * 8;
    const unsigned short* gB = Bm + (col0 + srow) * 768 + cdat * 8;

#define STG_A(buf, q, koff) GLD16(gA + (q) * 49152 + (koff), (char*)As + (buf) * 32768 + (q) * 8192 + wv * 1024)
#define STG_B(buf, q, koff) GLD16(gB + (q) * 49152 + (koff), (char*)Bs + (buf) * 32768 + (q) * 8192 + wv * 1024)

    // fragment read offsets (ushort units), swizzle-matched:
    // addr = buf*16384 + row*64 + ((ks*4 + kc) ^ (row&7))*8, row = base + frow
    const int sx = frow & 7;
    const int aRowBase = (wr * 128 + frow) * 64;
    const int bRowBase = (wc * 64 + frow) * 64;
    const int sl0 = ((0 + kc) ^ sx) * 8;   // K-sub 0
    const int sl1 = ((4 + kc) ^ sx) * 8;   // K-sub 1

    bf16x8 aF[4][2], bN0[2][2], bN1[2][2];

#define READ_A(buf, mh)                                                         \
    _Pragma("unroll") for (int m = 0; m < 4; ++m) {                             \
        aF[m][0] = *(const bf16x8*)(As + (buf) * 16384 + aRowBase + ((mh) * 4 + m) * 1024 + sl0); \
        aF[m][1] = *(const bf16x8*)(As + (buf) * 16384 + aRowBase + ((mh) * 4 + m) * 1024 + sl1); \
    }
#define READ_B(buf, nh, arr)                                                    \
    _Pragma("unroll") for (int n = 0; n < 2; ++n) {                             \
        arr[n][0] = *(const bf16x8*)(Bs + (buf) * 16384 + bRowBase + ((nh) * 2 + n) * 1024 + sl0); \
        arr[n][1] = *(const bf16x8*)(Bs + (buf) * 16384 + bRowBase + ((nh) * 2 + n) * 1024 + sl1); \
    }
#define MFMA_Q(mh, nh, arr)                                                     \
    __builtin_amdgcn_s_setprio(1);                                              \
    _Pragma("unroll") for (int m = 0; m < 4; ++m)                               \
    _Pragma("unroll") for (int n = 0; n < 2; ++n)                               \
    _Pragma("unroll") for (int ks = 0; ks < 2; ++ks)                            \
        acc[(mh) * 4 + m][(nh) * 2 + n] = __builtin_amdgcn_mfma_f32_16x16x32_bf16( \
            aF[m][ks], arr[n][ks], acc[(mh) * 4 + m][(nh) * 2 + n], 0, 0, 0);   \
    __builtin_amdgcn_s_setprio(0);

    // prologue: tile 0 complete (8 issues, oldest) + tile 1 minus Aq1/Aq3
    STG_A(0, 0, 0); STG_A(0, 1, 0); STG_A(0, 2, 0); STG_A(0, 3, 0);
    STG_B(0, 0, 0); STG_B(0, 1, 0); STG_B(0, 2, 0); STG_B(0, 3, 0);
    STG_A(1, 0, 64); STG_A(1, 2, 64);
    STG_B(1, 0, 64); STG_B(1, 1, 64); STG_B(1, 2, 64); STG_B(1, 3, 64);
    VM_LGKM_BAR(6);   // forces the oldest 8 (= tile 0) landed

    for (int i = 0; i < 5; ++i) {
        const int k1 = (2 * i + 1) * 64, k2 = (2 * i + 2) * 64, k3 = (2 * i + 3) * 64;
        // P1: Qa(buf0)
        READ_A(0, 0); READ_B(0, 0, bN0);
        STG_A(1, 1, k1); STG_A(1, 3, k1);
        MFMA_Q(0, 0, bN0);
        LGKM_BAR;
        // P2: Qb(buf0)
        READ_B(0, 1, bN1);
        STG_A(0, 0, k2); STG_A(0, 2, k2);
        MFMA_Q(0, 1, bN1);
        LGKM_BAR;
        // P3: Qc(buf0)
        READ_A(0, 1);
        STG_B(0, 0, k2); STG_B(0, 1, k2);
        MFMA_Q(1, 1, bN1);
        LGKM_BAR;
        // P4: Qd(buf0) — register reuse only
        STG_B(0, 2, k2); STG_B(0, 3, k2);
        MFMA_Q(1, 0, bN0);
        VM_LGKM_BAR(6);
        // P5: Qa(buf1)
        READ_A(1, 0); READ_B(1, 0, bN0);
        STG_A(0, 1, k2); STG_A(0, 3, k2);
        MFMA_Q(0, 0, bN0);
        LGKM_BAR;
        // P6: Qb(buf1)
        READ_B(1, 1, bN1);
        STG_A(1, 0, k3); STG_A(1, 2, k3);
        MFMA_Q(0, 1, bN1);
        LGKM_BAR;
        // P7: Qc(buf1)
        READ_A(1, 1);
        STG_B(1, 0, k3); STG_B(1, 1, k3);
        MFMA_Q(1, 1, bN1);
        LGKM_BAR;
        // P8: Qd(buf1)
        STG_B(1, 2, k3); STG_B(1, 3, k3);
        MFMA_Q(1, 0, bN0);
        VM_LGKM_BAR(6);
    }

    // epilogue: tiles 10 (buf0) and 11 (buf1); only P1's stage remains
    {
        // P1
        READ_A(0, 0); READ_B(0, 0, bN0);
        STG_A(1, 1, 704); STG_A(1, 3, 704);   // tile 11 tail
        MFMA_Q(0, 0, bN0);
        LGKM_BAR;
        // P2
        READ_B(0, 1, bN1);
        MFMA_Q(0, 1, bN1);
        LGKM_BAR;
        // P3
        READ_A(0, 1);
        MFMA_Q(1, 1, bN1);
        LGKM_BAR;
        // P4 — forces tile 11 body (i4 P6..P8 issues) landed
        MFMA_Q(1, 0, bN0);
        VM_LGKM_BAR(2);
        // P5
        READ_A(1, 0); READ_B(1, 0, bN0);
        MFMA_Q(0, 0, bN0);
        LGKM_BAR;
        // P6 — forces tile 11 Aq1/Aq3 landed; vmcnt==0 from here on
        READ_B(1, 1, bN1);
        MFMA_Q(0, 1, bN1);
        VM_LGKM_BAR(0);
        // P7
        READ_A(1, 1);
        MFMA_Q(1, 1, bN1);
        // P8
        MFMA_Q(1, 0, bN0);
    }
#undef READ_A
#undef READ_B
#undef MFMA_Q
#undef STG_A
#undef STG_B

    if (mode == 0) {
        const int part = row0 / 768;        // 768 % 256 == 0: uniform per block
        const int bb = col0 / 2048;         // 2048 % 256 == 0: uniform per block
        unsigned short* Xp = outb + (size_t)(part * 8 + bb) * 768 * 2048;
        const int drow0 = row0 - part * 768 + wr * 128 + (lane >> 4) * 4;
        const int lcol0 = col0 - bb * 2048 + wc * 64 + frow;
        #pragma unroll
        for (int m = 0; m < 8; ++m) {
            #pragma unroll
            for (int rr = 0; rr < 4; ++rr) {
                const int dd = drow0 + m * 16 + rr;
                const float bn = bias[row0 + wr * 128 + (lane >> 4) * 4 + m * 16 + rr];
                #pragma unroll
                for (int n = 0; n < 4; ++n)
                    Xp[dd * 2048 + lcol0 + n * 16] = f2b(acc[m][n][rr] + bn);
            }
        }
    } else {
        #pragma unroll
        for (int m = 0; m < 8; ++m) {
            #pragma unroll
            for (int rr = 0; rr < 4; ++rr) {
                const int mm = row0 + wr * 128 + (lane >> 4) * 4 + m * 16 + rr;
                #pragma unroll
                for (int n = 0; n < 4; ++n) {
                    const int nn = col0 + wc * 64 + n * 16 + frow;
                    outf[(size_t)mm * 768 + nn] = acc[m][n][rr] + bias[nn];
                }
            }
        }
    }
}

// --------------------- fused conv4 + gate + FFT conv -----------------------
__device__ __forceinline__ void conv6(const unsigned short* __restrict__ p,
                                      const float* w, float bias, int t, float* out8)
{
    const uint4 m = *(const uint4*)(p + 8 * t);
    uint2 q = make_uint2(0u, 0u);
    if (t) q = *(const uint2*)(p + 8 * t - 4);
    float s[12];
    s[0] = b2f_lo(q.x); s[1] = b2f_hi(q.x); s[2] = b2f_lo(q.y); s[3] = b2f_hi(q.y);
    s[4] = b2f_lo(m.x); s[5] = b2f_hi(m.x); s[6] = b2f_lo(m.y); s[7] = b2f_hi(m.y);
    s[8] = b2f_lo(m.z); s[9] = b2f_hi(m.z); s[10] = b2f_lo(m.w); s[11] = b2f_hi(m.w);
    #pragma unroll
    for (int i = 0; i < 8; ++i)
        out8[i] = bias + w[0] * s[i + 1] + w[1] * s[i + 2] + w[2] * s[i + 3] + w[3] * s[i + 4];
}

// grid (768, 4): x=d (same-d blocks 768 apart -> same XCD -> Kf L2 reuse)
__global__ __launch_bounds__(256, 4) void fft_conv_kernel(
    const unsigned short* __restrict__ X, const float2* __restrict__ Kf,
    const float* __restrict__ x1_s, const float* __restrict__ x2_s, const float* __restrict__ v_s,
    const float* __restrict__ x1_sb, const float* __restrict__ x2_sb, const float* __restrict__ v_sb,
    const float* __restrict__ D_bias, unsigned short* __restrict__ Y)
{
    __shared__ __align__(16) float2 lds[4352];
    unsigned* ldsu = (unsigned*)lds;
    const int d = blockIdx.x, jp = blockIdx.y, t = threadIdx.x;
    const int b0 = jp * 2, b1 = b0 + 1;

    float w1[4], w2[4], wv[4];
    #pragma unroll
    for (int j = 0; j < 4; ++j) { w1[j] = x1_s[d * 4 + j]; w2[j] = x2_s[d * 4 + j]; wv[j] = v_s[d * 4 + j]; }
    const float bc1 = x1_sb[d], bc2 = x2_sb[d], bcv = v_sb[d], Db = D_bias[d];

    const unsigned short* px1a = X + ((size_t)(0 * 8 + b0) * 768 + d) * 2048;
    const unsigned short* px2a = X + ((size_t)(1 * 8 + b0) * 768 + d) * 2048;
    const unsigned short* pva  = X + ((size_t)(2 * 8 + b0) * 768 + d) * 2048;
    const unsigned short* px1b = X + ((size_t)(0 * 8 + b1) * 768 + d) * 2048;
    const unsigned short* px2b = X + ((size_t)(1 * 8 + b1) * 768 + d) * 2048;
    const unsigned short* pvb  = X + ((size_t)(2 * 8 + b1) * 768 + d) * 2048;

    {
        float x1a[8], x2a[8], vva[8];
        conv6(px1a, w1, bc1, t, x1a);
        conv6(px2a, w2, bc2, t, x2a);
        conv6(pva,  wv, bcv, t, vva);
        float x1b[8], x2b[8], vvb[8];
        conv6(px1b, w1, bc1, t, x1b);
        conv6(px2b, w2, bc2, t, x2b);
        conv6(pvb,  wv, bcv, t, vvb);
        unsigned vh_pk[8], c2_pk[8];
        #pragma unroll
        for (int i = 0; i < 8; ++i) {
            vh_pk[i] = (unsigned)f2b(vva[i] * x1a[i]) | ((unsigned)f2b(vvb[i] * x1b[i]) << 16);
            c2_pk[i] = (unsigned)f2b(x2a[i]) | ((unsigned)f2b(x2b[i]) << 16);
        }
        *(uint4*)(ldsu + 8 * t)        = make_uint4(vh_pk[0], vh_pk[1], vh_pk[2], vh_pk[3]);
        *(uint4*)(ldsu + 8 * t + 4)    = make_uint4(vh_pk[4], vh_pk[5], vh_pk[6], vh_pk[7]);
        *(uint4*)(ldsu + 2048 + 8 * t)     = make_uint4(c2_pk[0], c2_pk[1], c2_pk[2], c2_pk[3]);
        *(uint4*)(ldsu + 2048 + 8 * t + 4) = make_uint4(c2_pk[4], c2_pk[5], c2_pk[6], c2_pk[7]);
    }
    __syncthreads();

    unsigned vhp[8], c2p[8];
    float2 x[16];
    #pragma unroll
    for (int r = 0; r < 8; ++r) {
        const unsigned u = ldsu[r * 256 + t];
        vhp[r] = u;
        x[r] = make_float2(b2f_lo(u), b2f_hi(u));
    }
    #pragma unroll
    for (int r = 0; r < 8; ++r) c2p[r] = ldsu[2048 + r * 256 + t];

    const float2* kf = Kf + (size_t)d * 4096;
    float2 kfr[16];
    #pragma unroll
    for (int k3 = 0; k3 < 16; ++k3) kfr[k3] = kf[k3 * 256 + t];

    __syncthreads();

    fft4096_fwd(x, lds, t);
    #pragma unroll
    for (int k3 = 0; k3 < 16; ++k3) x[k3] = cmul(x[k3], kfr[k3]);
    fft4096_inv(x, lds, t);

    const float invN = 1.0f / 4096.0f;
    unsigned short* ya = Y + ((size_t)b0 * 768 + d) * 2048;
    unsigned short* yb = Y + ((size_t)b1 * 768 + d) * 2048;
    #pragma unroll
    for (int n1 = 0; n1 < 8; ++n1) {
        const int l = n1 * 256 + t;
        const float va = b2f_lo(vhp[n1]);
        const float vb = b2f_hi(vhp[n1]);
        const float ca = b2f_lo(c2p[n1]);
        const float cb = b2f_hi(c2p[n1]);
        ya[l] = f2b((x[n1].x * invN + va * Db) * ca);
        yb[l] = f2b((x[n1].y * invN + vb * Db) * cb);
    }
}

// --------------------------------- launch ----------------------------------
extern "C" void kernel_launch(void* const* d_in, const int* in_sizes, int n_in,
                              void* d_out, int out_size, void* d_ws, size_t ws_size,
                              hipStream_t stream)
{
    (void)in_sizes; (void)n_in; (void)out_size; (void)ws_size;
    const float* u      = (const float*)d_in[0];
    const float* in_W   = (const float*)d_in[1];
    const float* in_b   = (const float*)d_in[2];
    const float* out_W  = (const float*)d_in[3];
    const float* out_b  = (const float*)d_in[4];
    const float* x1_s   = (const float*)d_in[5];
    const float* x2_s   = (const float*)d_in[6];
    const float* v_s    = (const float*)d_in[7];
    const float* x1_sb  = (const float*)d_in[8];
    const float* x2_sb  = (const float*)d_in[9];
    const float* v_sb   = (const float*)d_in[10];
    const float* D_bias = (const float*)d_in[11];
    const float* z      = (const float*)d_in[12];
    const float* sf     = (const float*)d_in[13];
    const float* eo     = (const float*)d_in[14];
    const float* eo_b   = (const float*)d_in[15];
    const float* oo1    = (const float*)d_in[16];
    const float* oo1_b  = (const float*)d_in[17];
    const float* oo2    = (const float*)d_in[18];
    const float* oo2_b  = (const float*)d_in[19];
    const float* oh     = (const float*)d_in[20];
    float* out = (float*)d_out;

    char* ws = (char*)d_ws;
    unsigned short* Xbf  = (unsigned short*)(ws + 0);          //  75,497,472 X[3][8][768][2048] bf16
    unsigned short* Ybf  = (unsigned short*)(ws + 75497472);   //  25,165,824 Y[8][768][2048] bf16
    unsigned short* ubYt = (unsigned short*)(ws + 100663296);  //  25,165,824 ub, later aliased as Yt
    unsigned short* Wt   = (unsigned short*)(ws + 125829120);  //   3,538,944 Wt[2304][768] bf16
    unsigned short* W2t  = (unsigned short*)(ws + 129368064);  //   1,179,648 W2t[768][768] bf16
    float*          kfil = (float*)(ws + 130547712);           //   6,291,456 k[768][2048] fp32
    float2*         Kf   = (float2*)(ws + 136839168);          //  25,165,824 K_f[768][16][256] cplx (permuted)

    static int attr_set = 0;
    if (!attr_set) {
        (void)hipFuncSetAttribute(reinterpret_cast<const void*>(gemm256_kernel),
                                  hipFuncAttributeMaxDynamicSharedMemorySize, 131072);
        attr_set = 1;
    }

    filter_k_kernel<<<256, 256, 0, stream>>>(z, sf, eo, eo_b, oo1, oo1_b, oo2, oo2_b, oh, kfil);
    filter_fft_kernel<<<768, 256, 0, stream>>>(kfil, Kf);
    convert_u_kernel<<<12288, 256, 0, stream>>>(u, ubYt);
    transpose_W_kernel<<<dim3(72, 24), 256, 0, stream>>>(in_W, Wt, 768, 2304);
    transpose_W_kernel<<<dim3(24, 24), 256, 0, stream>>>(out_W, W2t, 768, 768);
    gemm256_kernel<<<dim3(64, 9), 512, 131072, stream>>>(Wt, ubYt, in_b, Xbf, nullptr, 0);
    fft_conv_kernel<<<dim3(768, 4), 256, 0, stream>>>(Xbf, Kf, x1_s, x2_s, v_s, x1_sb, x2_sb, v_sb, D_bias, Ybf);
    transpose_Y_kernel<<<12288, 256, 0, stream>>>(Ybf, ubYt);
    gemm256_kernel<<<dim3(64, 3), 512, 131072, stream>>>(ubYt, W2t, out_b, nullptr, out, 1);
}